// Round 1
// baseline (598.740 us; speedup 1.0000x reference)
//
#include <hip/hip_runtime.h>
#include <hip/hip_bf16.h>
#include <cstdint>

typedef __bf16 bf16_t;
typedef __attribute__((ext_vector_type(4))) __bf16 bf16x4;
typedef __attribute__((ext_vector_type(8))) __bf16 bf16x8;
typedef __attribute__((ext_vector_type(4))) float f32x4;

#define B_SZ 2
#define S_SZ 2048
#define D_MODEL 1024
#define NUM_HEADS 16
#define HEAD_DIM 64
#define FF_DIM 4096
#define M_ROWS (B_SZ * S_SZ)   // 4096

// ---------------------------------------------------------------------------
// async global->LDS (16B per lane, wave-uniform LDS base + lane*16)
// ---------------------------------------------------------------------------
__device__ __forceinline__ void gload_lds16(const void* g, void* lds) {
    __builtin_amdgcn_global_load_lds(
        (const __attribute__((address_space(1))) void*)(uintptr_t)g,
        (__attribute__((address_space(3))) void*)(uint32_t)(uintptr_t)lds,
        16, 0, 0);
}

__device__ __forceinline__ f32x4 mfma16(bf16x8 a, bf16x8 b, f32x4 c) {
    return __builtin_amdgcn_mfma_f32_16x16x32_bf16(a, b, c, 0, 0, 0);
}

// ---------------------------------------------------------------------------
// elementwise cast f32 -> bf16 (4 elems/thread)
// ---------------------------------------------------------------------------
__global__ __launch_bounds__(256) void cast_f32_bf16(const float* __restrict__ in,
                                                     bf16_t* __restrict__ out) {
    size_t i = ((size_t)blockIdx.x * 256 + threadIdx.x) * 4;
    float4 v = *(const float4*)(in + i);
    bf16x4 o;
    o[0] = (bf16_t)v.x; o[1] = (bf16_t)v.y; o[2] = (bf16_t)v.z; o[3] = (bf16_t)v.w;
    *(bf16x4*)(out + i) = o;
}

// ---------------------------------------------------------------------------
// W [K][N] f32  ->  WT [N][K] bf16   (32x32 tiles)
// ---------------------------------------------------------------------------
__global__ __launch_bounds__(256) void transpose_cast_w(const float* __restrict__ W,
                                                        bf16_t* __restrict__ WT,
                                                        int K, int N) {
    __shared__ float t[32][33];
    int tid = threadIdx.x;
    int rr = tid >> 3, cc = (tid & 7) * 4;
    int k0 = blockIdx.x * 32, n0 = blockIdx.y * 32;
    float4 v = *(const float4*)(W + (size_t)(k0 + rr) * N + n0 + cc);
    t[rr][cc + 0] = v.x; t[rr][cc + 1] = v.y; t[rr][cc + 2] = v.z; t[rr][cc + 3] = v.w;
    __syncthreads();
    bf16x4 o;
    o[0] = (bf16_t)t[cc + 0][rr]; o[1] = (bf16_t)t[cc + 1][rr];
    o[2] = (bf16_t)t[cc + 2][rr]; o[3] = (bf16_t)t[cc + 3][rr];
    *(bf16x4*)(WT + (size_t)(n0 + rr) * K + k0 + cc) = o;
}

// ---------------------------------------------------------------------------
// Vp [B*S][1024] bf16 -> VT [B][H][64][S] bf16
// grid: (S/32, 2, B*H)
// ---------------------------------------------------------------------------
__global__ __launch_bounds__(256) void transpose_v(const bf16_t* __restrict__ Vp,
                                                   bf16_t* __restrict__ VT) {
    __shared__ bf16_t t[32][34];
    int tid = threadIdx.x;
    int rr = tid >> 3, cc = (tid & 7) * 4;
    int bh = blockIdx.z;            // b*16+h
    int b = bh >> 4, h = bh & 15;
    int s0 = blockIdx.x * 32, d0 = blockIdx.y * 32;
    bf16x4 v = *(const bf16x4*)(Vp + ((size_t)(b * S_SZ + s0 + rr)) * D_MODEL + h * HEAD_DIM + d0 + cc);
    t[rr][cc + 0] = v[0]; t[rr][cc + 1] = v[1]; t[rr][cc + 2] = v[2]; t[rr][cc + 3] = v[3];
    __syncthreads();
    bf16x4 o;
    o[0] = t[cc + 0][rr]; o[1] = t[cc + 1][rr]; o[2] = t[cc + 2][rr]; o[3] = t[cc + 3][rr];
    *(bf16x4*)(VT + ((size_t)(bh * HEAD_DIM + d0 + rr)) * S_SZ + s0 + cc) = o;
}

// ---------------------------------------------------------------------------
// GEMM: C[M][N] = A[M][K] @ Bt[N][K]^T + bias  (A,Bt bf16; acc fp32)
// 128x128 tile, BK=32, 4 waves (each 64x64 = 4x4 frags of 16x16x32)
// ---------------------------------------------------------------------------
template<bool RELU, bool OUT_BF16, bool OUT_F32>
__global__ __launch_bounds__(256) void gemm_bt(const bf16_t* __restrict__ A,
                                               const bf16_t* __restrict__ Bt,
                                               const float* __restrict__ bias,
                                               float* __restrict__ Cf,
                                               bf16_t* __restrict__ Cb,
                                               int M, int N, int K) {
    __shared__ bf16_t sA[128 * 32];
    __shared__ bf16_t sB[128 * 32];
    const int tid = threadIdx.x;
    const int lane = tid & 63, wave = tid >> 6;
    const int g = lane >> 4, r = lane & 15;
    const int m0 = blockIdx.x * 128, n0 = blockIdx.y * 128;
    const int wm = (wave >> 1) * 64, wn = (wave & 1) * 64;

    const bf16_t* Ablk = A + (size_t)m0 * K;
    const bf16_t* Bblk = Bt + (size_t)n0 * K;
    const int c0 = wave * 64 + lane;   // chunk 0..255
    const int c1 = c0 + 256;           // chunk 256..511

    f32x4 acc[4][4];
#pragma unroll
    for (int i = 0; i < 4; i++)
#pragma unroll
        for (int j = 0; j < 4; j++)
#pragma unroll
            for (int e = 0; e < 4; e++) acc[i][j][e] = 0.f;

    for (int k0 = 0; k0 < K; k0 += 32) {
        // stage A[128][32] and B[128][32] (8KB each); 2 chunks of 1KB per wave each
        gload_lds16(Ablk + (size_t)(c0 >> 2) * K + k0 + (c0 & 3) * 8, sA + wave * 512);
        gload_lds16(Ablk + (size_t)(c1 >> 2) * K + k0 + (c1 & 3) * 8, sA + 2048 + wave * 512);
        gload_lds16(Bblk + (size_t)(c0 >> 2) * K + k0 + (c0 & 3) * 8, sB + wave * 512);
        gload_lds16(Bblk + (size_t)(c1 >> 2) * K + k0 + (c1 & 3) * 8, sB + 2048 + wave * 512);
        __syncthreads();   // drains vmcnt -> staged data visible

        bf16x8 a[4], b[4];
#pragma unroll
        for (int i = 0; i < 4; i++)
            a[i] = *(const bf16x8*)(sA + (wm + i * 16 + r) * 32 + g * 8);
#pragma unroll
        for (int j = 0; j < 4; j++)
            b[j] = *(const bf16x8*)(sB + (wn + j * 16 + r) * 32 + g * 8);
#pragma unroll
        for (int i = 0; i < 4; i++)
#pragma unroll
            for (int j = 0; j < 4; j++)
                acc[i][j] = mfma16(a[i], b[j], acc[i][j]);
        __syncthreads();   // all reads done before next stage overwrites
    }

    // epilogue: D frag: col = r (+16j), row = g*4+rr (+16i)
#pragma unroll
    for (int j = 0; j < 4; j++) {
        int n = n0 + wn + j * 16 + r;
        float bv = bias[n];
#pragma unroll
        for (int i = 0; i < 4; i++) {
#pragma unroll
            for (int rr = 0; rr < 4; rr++) {
                int mrow = m0 + wm + i * 16 + g * 4 + rr;
                float val = acc[i][j][rr] + bv;
                if (RELU) val = fmaxf(val, 0.f);
                if (OUT_F32) Cf[(size_t)mrow * N + n] = val;
                if (OUT_BF16) Cb[(size_t)mrow * N + n] = (bf16_t)val;
            }
        }
    }
}

// ---------------------------------------------------------------------------
// Flash attention: Qp,Kp [B*S][1024] bf16 (n = h*64+d), VT [B][H][64][S] bf16
// -> Oa [B*S][1024] bf16.  grid (S/64, H, B), 256 threads (4 waves x 16 Q-rows)
// ---------------------------------------------------------------------------
__global__ __launch_bounds__(256) void flash_attn(const bf16_t* __restrict__ Qp,
                                                  const bf16_t* __restrict__ Kp,
                                                  const bf16_t* __restrict__ VT,
                                                  bf16_t* __restrict__ Oa) {
    __shared__ bf16_t sP[4][16 * 64];
    const int tid = threadIdx.x;
    const int lane = tid & 63, wave = tid >> 6;
    const int g = lane >> 4, r = lane & 15;
    const int h = blockIdx.y, b = blockIdx.z;
    const int q0 = blockIdx.x * 64 + wave * 16;

    const bf16_t* Qb = Qp + (size_t)b * S_SZ * D_MODEL + h * HEAD_DIM;
    const bf16_t* Kb = Kp + (size_t)b * S_SZ * D_MODEL + h * HEAD_DIM;
    const bf16_t* Vb = VT + ((size_t)(b * NUM_HEADS + h) * HEAD_DIM) * S_SZ;

    // Q A-frags: row = r, k = g*8+i (+32*kk)
    bf16x8 aq[2];
    aq[0] = *(const bf16x8*)(Qb + (size_t)(q0 + r) * D_MODEL + g * 8);
    aq[1] = *(const bf16x8*)(Qb + (size_t)(q0 + r) * D_MODEL + 32 + g * 8);

    float m[4], l[4];
    f32x4 o[4];
#pragma unroll
    for (int rr = 0; rr < 4; rr++) { m[rr] = -1e30f; l[rr] = 0.f; }
#pragma unroll
    for (int j = 0; j < 4; j++)
#pragma unroll
        for (int e = 0; e < 4; e++) o[j][e] = 0.f;

    const float scale = 0.125f;   // 1/sqrt(64)
    bf16_t* Pw = sP[wave];

    for (int kv0 = 0; kv0 < S_SZ; kv0 += 64) {
        // S = Q K^T : n = kv index, k = d
        f32x4 s[4];
#pragma unroll
        for (int j = 0; j < 4; j++) {
#pragma unroll
            for (int e = 0; e < 4; e++) s[j][e] = 0.f;
            const bf16_t* krow = Kb + (size_t)(kv0 + j * 16 + r) * D_MODEL;
            bf16x8 bk0 = *(const bf16x8*)(krow + g * 8);
            bf16x8 bk1 = *(const bf16x8*)(krow + 32 + g * 8);
            s[j] = mfma16(aq[0], bk0, s[j]);
            s[j] = mfma16(aq[1], bk1, s[j]);
        }
        // online softmax: lane holds rows g*4+rr, col r+16j
        float p[4][4];
#pragma unroll
        for (int rr = 0; rr < 4; rr++) {
            float sv[4];
            float mx = -1e30f;
#pragma unroll
            for (int j = 0; j < 4; j++) { sv[j] = s[j][rr] * scale; mx = fmaxf(mx, sv[j]); }
#pragma unroll
            for (int off = 1; off < 16; off <<= 1) mx = fmaxf(mx, __shfl_xor(mx, off));
            float mnew = fmaxf(m[rr], mx);
            float sum = 0.f;
#pragma unroll
            for (int j = 0; j < 4; j++) { float e = __expf(sv[j] - mnew); p[j][rr] = e; sum += e; }
#pragma unroll
            for (int off = 1; off < 16; off <<= 1) sum += __shfl_xor(sum, off);
            float alpha = __expf(m[rr] - mnew);
            l[rr] = l[rr] * alpha + sum;
            m[rr] = mnew;
#pragma unroll
            for (int j = 0; j < 4; j++) o[j][rr] *= alpha;
        }
        // P -> LDS (bf16), fix layout D->A
#pragma unroll
        for (int j = 0; j < 4; j++)
#pragma unroll
            for (int rr = 0; rr < 4; rr++)
                Pw[(g * 4 + rr) * 64 + j * 16 + r] = (bf16_t)p[j][rr];
        __syncthreads();
        // O += P V : A row = r (q), k = kv ; B col = d = r+16j, k = kv
#pragma unroll
        for (int kk = 0; kk < 2; kk++) {
            bf16x8 ap = *(const bf16x8*)(Pw + r * 64 + kk * 32 + g * 8);
#pragma unroll
            for (int j = 0; j < 4; j++) {
                bf16x8 bv = *(const bf16x8*)(Vb + (size_t)(j * 16 + r) * S_SZ + kv0 + kk * 32 + g * 8);
                o[j] = mfma16(ap, bv, o[j]);
            }
        }
        __syncthreads();
    }

    // normalize + write: col d = r+16j, row q = g*4+rr
#pragma unroll
    for (int j = 0; j < 4; j++) {
#pragma unroll
        for (int rr = 0; rr < 4; rr++) {
            float val = o[j][rr] / l[rr];
            Oa[((size_t)b * S_SZ + q0 + g * 4 + rr) * D_MODEL + h * HEAD_DIM + j * 16 + r] = (bf16_t)val;
        }
    }
}

// ---------------------------------------------------------------------------
// LayerNorm over 1024, fused residual add. 1 block = 1 row, 256 threads x4.
// ---------------------------------------------------------------------------
__global__ __launch_bounds__(256) void ln_fused(const float* __restrict__ A,
                                                const float* __restrict__ R,
                                                const float* __restrict__ gamma,
                                                const float* __restrict__ beta,
                                                float* __restrict__ Xf,
                                                bf16_t* __restrict__ Xb) {
    __shared__ float red[8];
    int row = blockIdx.x, tid = threadIdx.x;
    size_t base = (size_t)row * D_MODEL + tid * 4;
    float4 a = *(const float4*)(A + base);
    float4 rv = *(const float4*)(R + base);
    float v0 = a.x + rv.x, v1 = a.y + rv.y, v2 = a.z + rv.z, v3 = a.w + rv.w;
    float s = v0 + v1 + v2 + v3;
    float q = v0 * v0 + v1 * v1 + v2 * v2 + v3 * v3;
#pragma unroll
    for (int off = 32; off; off >>= 1) { s += __shfl_down(s, off); q += __shfl_down(q, off); }
    if ((tid & 63) == 0) { red[tid >> 6] = s; red[4 + (tid >> 6)] = q; }
    __syncthreads();
    s = red[0] + red[1] + red[2] + red[3];
    q = red[4] + red[5] + red[6] + red[7];
    float mean = s * (1.f / D_MODEL);
    float var = q * (1.f / D_MODEL) - mean * mean;
    float rstd = rsqrtf(var + 1e-5f);
    float4 gm = *(const float4*)(gamma + tid * 4);
    float4 bt = *(const float4*)(beta + tid * 4);
    float y0 = (v0 - mean) * rstd * gm.x + bt.x;
    float y1 = (v1 - mean) * rstd * gm.y + bt.y;
    float y2 = (v2 - mean) * rstd * gm.z + bt.z;
    float y3 = (v3 - mean) * rstd * gm.w + bt.w;
    float4 yo; yo.x = y0; yo.y = y1; yo.z = y2; yo.w = y3;
    *(float4*)(Xf + base) = yo;
    if (Xb) {
        bf16x4 ob; ob[0] = (bf16_t)y0; ob[1] = (bf16_t)y1; ob[2] = (bf16_t)y2; ob[3] = (bf16_t)y3;
        *(bf16x4*)(Xb + base) = ob;
    }
}

// ---------------------------------------------------------------------------
extern "C" void kernel_launch(void* const* d_in, const int* in_sizes, int n_in,
                              void* d_out, int out_size, void* d_ws, size_t ws_size,
                              hipStream_t stream) {
    const float* value = (const float*)d_in[0];
    const float* key   = (const float*)d_in[1];
    const float* query = (const float*)d_in[2];
    const float* wq = (const float*)d_in[3];
    const float* bq = (const float*)d_in[4];
    const float* wk = (const float*)d_in[5];
    const float* bk = (const float*)d_in[6];
    const float* wv = (const float*)d_in[7];
    const float* bv = (const float*)d_in[8];
    const float* wo = (const float*)d_in[9];
    const float* bo = (const float*)d_in[10];
    const float* g1 = (const float*)d_in[11];
    const float* beta1 = (const float*)d_in[12];
    const float* w1 = (const float*)d_in[13];
    const float* b1 = (const float*)d_in[14];
    const float* w2 = (const float*)d_in[15];
    const float* b2 = (const float*)d_in[16];
    const float* g2 = (const float*)d_in[17];
    const float* beta2 = (const float*)d_in[18];
    (void)in_sizes; (void)n_in; (void)out_size; (void)ws_size;

    const size_t MB = 1ull << 20;
    char* ws = (char*)d_ws;
    bf16_t* wqT = (bf16_t*)(ws + 0 * MB);   // [1024][1024]
    bf16_t* wkT = (bf16_t*)(ws + 2 * MB);
    bf16_t* wvT = (bf16_t*)(ws + 4 * MB);
    bf16_t* woT = (bf16_t*)(ws + 6 * MB);
    bf16_t* w1T = (bf16_t*)(ws + 8 * MB);   // [4096][1024]
    bf16_t* w2T = (bf16_t*)(ws + 16 * MB);  // [1024][4096]
    bf16_t* q_bf = (bf16_t*)(ws + 24 * MB); // [4096][1024]
    bf16_t* k_bf = (bf16_t*)(ws + 32 * MB);
    bf16_t* v_bf = (bf16_t*)(ws + 40 * MB);
    bf16_t* Qp  = (bf16_t*)(ws + 48 * MB);
    bf16_t* Kp  = (bf16_t*)(ws + 56 * MB);
    bf16_t* Vp  = (bf16_t*)(ws + 64 * MB);
    bf16_t* VT  = (bf16_t*)(ws + 72 * MB);  // [B][H][64][S]
    bf16_t* attn = (bf16_t*)(ws + 24 * MB); // reuse q_bf
    float*  attn_out = (float*)(ws + 80 * MB); // [4096][1024] f32
    float*  x_f = (float*)(ws + 96 * MB);
    bf16_t* x_b = (bf16_t*)(ws + 112 * MB);
    bf16_t* h_b = (bf16_t*)(ws + 40 * MB);  // [4096][4096] bf16, reuse v_bf..Vp
    float*  y_f = (float*)(ws + 80 * MB);   // reuse attn_out

    dim3 blk(256);

    // 1) casts + weight transposes
    cast_f32_bf16<<<4096, blk, 0, stream>>>(query, q_bf);
    cast_f32_bf16<<<4096, blk, 0, stream>>>(key, k_bf);
    cast_f32_bf16<<<4096, blk, 0, stream>>>(value, v_bf);
    transpose_cast_w<<<dim3(32, 32), blk, 0, stream>>>(wq, wqT, 1024, 1024);
    transpose_cast_w<<<dim3(32, 32), blk, 0, stream>>>(wk, wkT, 1024, 1024);
    transpose_cast_w<<<dim3(32, 32), blk, 0, stream>>>(wv, wvT, 1024, 1024);
    transpose_cast_w<<<dim3(32, 32), blk, 0, stream>>>(wo, woT, 1024, 1024);
    transpose_cast_w<<<dim3(32, 128), blk, 0, stream>>>(w1, w1T, 1024, 4096);
    transpose_cast_w<<<dim3(128, 32), blk, 0, stream>>>(w2, w2T, 4096, 1024);

    // 2) QKV projections (bf16 out)
    gemm_bt<false, true, false><<<dim3(32, 8), blk, 0, stream>>>(q_bf, wqT, bq, nullptr, Qp, M_ROWS, D_MODEL, D_MODEL);
    gemm_bt<false, true, false><<<dim3(32, 8), blk, 0, stream>>>(k_bf, wkT, bk, nullptr, Kp, M_ROWS, D_MODEL, D_MODEL);
    gemm_bt<false, true, false><<<dim3(32, 8), blk, 0, stream>>>(v_bf, wvT, bv, nullptr, Vp, M_ROWS, D_MODEL, D_MODEL);

    // 3) V transpose for PV B-operand
    transpose_v<<<dim3(64, 2, 32), blk, 0, stream>>>(Vp, VT);

    // 4) flash attention
    flash_attn<<<dim3(32, 16, 2), blk, 0, stream>>>(Qp, Kp, VT, attn);

    // 5) WO projection (f32 out)
    gemm_bt<false, false, true><<<dim3(32, 8), blk, 0, stream>>>(attn, woT, bo, attn_out, nullptr, M_ROWS, D_MODEL, D_MODEL);

    // 6) LN1: x = LN(attn_out + query)
    ln_fused<<<4096, blk, 0, stream>>>(attn_out, query, g1, beta1, x_f, x_b);

    // 7) FF1 + ReLU (bf16 out)
    gemm_bt<true, true, false><<<dim3(32, 32), blk, 0, stream>>>(x_b, w1T, b1, nullptr, h_b, M_ROWS, FF_DIM, D_MODEL);

    // 8) FF2 (f32 out)
    gemm_bt<false, false, true><<<dim3(32, 8), blk, 0, stream>>>(h_b, w2T, b2, y_f, nullptr, M_ROWS, D_MODEL, FF_DIM);

    // 9) LN2 -> d_out
    ln_fused<<<4096, blk, 0, stream>>>(y_f, x_f, g2, beta2, (float*)d_out, nullptr);
}

// Round 2
// 596.232 us; speedup vs baseline: 1.0042x; 1.0042x over previous
//
#include <hip/hip_runtime.h>
#include <hip/hip_bf16.h>
#include <cstdint>

typedef __bf16 bf16_t;
typedef __attribute__((ext_vector_type(4))) __bf16 bf16x4;
typedef __attribute__((ext_vector_type(8))) __bf16 bf16x8;
typedef __attribute__((ext_vector_type(4))) float f32x4;

#define B_SZ 2
#define S_SZ 2048
#define D_MODEL 1024
#define NUM_HEADS 16
#define HEAD_DIM 64
#define FF_DIM 4096
#define M_ROWS (B_SZ * S_SZ)   // 4096

// ---------------------------------------------------------------------------
// async global->LDS (16B per lane, wave-uniform LDS base + lane*16)
// ---------------------------------------------------------------------------
__device__ __forceinline__ void gload_lds16(const void* g, void* lds) {
    __builtin_amdgcn_global_load_lds(
        (const __attribute__((address_space(1))) void*)(uintptr_t)g,
        (__attribute__((address_space(3))) void*)(uint32_t)(uintptr_t)lds,
        16, 0, 0);
}

__device__ __forceinline__ f32x4 mfma16(bf16x8 a, bf16x8 b, f32x4 c) {
    return __builtin_amdgcn_mfma_f32_16x16x32_bf16(a, b, c, 0, 0, 0);
}

// ---------------------------------------------------------------------------
// elementwise cast f32 -> bf16 (4 elems/thread)
// ---------------------------------------------------------------------------
__global__ __launch_bounds__(256) void cast_f32_bf16(const float* __restrict__ in,
                                                     bf16_t* __restrict__ out) {
    size_t i = ((size_t)blockIdx.x * 256 + threadIdx.x) * 4;
    float4 v = *(const float4*)(in + i);
    bf16x4 o;
    o[0] = (bf16_t)v.x; o[1] = (bf16_t)v.y; o[2] = (bf16_t)v.z; o[3] = (bf16_t)v.w;
    *(bf16x4*)(out + i) = o;
}

// ---------------------------------------------------------------------------
// W [K][N] f32  ->  WT [N][K] bf16   (32x32 tiles)
// ---------------------------------------------------------------------------
__global__ __launch_bounds__(256) void transpose_cast_w(const float* __restrict__ W,
                                                        bf16_t* __restrict__ WT,
                                                        int K, int N) {
    __shared__ float t[32][33];
    int tid = threadIdx.x;
    int rr = tid >> 3, cc = (tid & 7) * 4;
    int k0 = blockIdx.x * 32, n0 = blockIdx.y * 32;
    float4 v = *(const float4*)(W + (size_t)(k0 + rr) * N + n0 + cc);
    t[rr][cc + 0] = v.x; t[rr][cc + 1] = v.y; t[rr][cc + 2] = v.z; t[rr][cc + 3] = v.w;
    __syncthreads();
    bf16x4 o;
    o[0] = (bf16_t)t[cc + 0][rr]; o[1] = (bf16_t)t[cc + 1][rr];
    o[2] = (bf16_t)t[cc + 2][rr]; o[3] = (bf16_t)t[cc + 3][rr];
    *(bf16x4*)(WT + (size_t)(n0 + rr) * K + k0 + cc) = o;
}

// ---------------------------------------------------------------------------
// Vp [B*S][1024] bf16 -> VT [B][H][64][S] bf16
// grid: (S/32, 2, B*H)
// ---------------------------------------------------------------------------
__global__ __launch_bounds__(256) void transpose_v(const bf16_t* __restrict__ Vp,
                                                   bf16_t* __restrict__ VT) {
    __shared__ bf16_t t[32][34];
    int tid = threadIdx.x;
    int rr = tid >> 3, cc = (tid & 7) * 4;
    int bh = blockIdx.z;            // b*16+h
    int b = bh >> 4, h = bh & 15;
    int s0 = blockIdx.x * 32, d0 = blockIdx.y * 32;
    bf16x4 v = *(const bf16x4*)(Vp + ((size_t)(b * S_SZ + s0 + rr)) * D_MODEL + h * HEAD_DIM + d0 + cc);
    t[rr][cc + 0] = v[0]; t[rr][cc + 1] = v[1]; t[rr][cc + 2] = v[2]; t[rr][cc + 3] = v[3];
    __syncthreads();
    bf16x4 o;
    o[0] = t[cc + 0][rr]; o[1] = t[cc + 1][rr]; o[2] = t[cc + 2][rr]; o[3] = t[cc + 3][rr];
    *(bf16x4*)(VT + ((size_t)(bh * HEAD_DIM + d0 + rr)) * S_SZ + s0 + cc) = o;
}

// ---------------------------------------------------------------------------
// GEMM: C[M][N] = A[M][K] @ Bt[N][K]^T + bias  (A,Bt bf16; acc fp32)
// 128x128 tile, BK=32, 4 waves (each 64x64 = 4x4 frags of 16x16x32)
// ---------------------------------------------------------------------------
template<bool RELU, bool OUT_BF16, bool OUT_F32>
__global__ __launch_bounds__(256) void gemm_bt(const bf16_t* __restrict__ A,
                                               const bf16_t* __restrict__ Bt,
                                               const float* __restrict__ bias,
                                               float* __restrict__ Cf,
                                               bf16_t* __restrict__ Cb,
                                               int M, int N, int K) {
    __shared__ bf16_t sA[128 * 32];
    __shared__ bf16_t sB[128 * 32];
    const int tid = threadIdx.x;
    const int lane = tid & 63, wave = tid >> 6;
    const int g = lane >> 4, r = lane & 15;
    const int m0 = blockIdx.x * 128, n0 = blockIdx.y * 128;
    const int wm = (wave >> 1) * 64, wn = (wave & 1) * 64;

    const bf16_t* Ablk = A + (size_t)m0 * K;
    const bf16_t* Bblk = Bt + (size_t)n0 * K;
    const int c0 = wave * 64 + lane;   // chunk 0..255
    const int c1 = c0 + 256;           // chunk 256..511

    f32x4 acc[4][4];
#pragma unroll
    for (int i = 0; i < 4; i++)
#pragma unroll
        for (int j = 0; j < 4; j++)
#pragma unroll
            for (int e = 0; e < 4; e++) acc[i][j][e] = 0.f;

    for (int k0 = 0; k0 < K; k0 += 32) {
        // stage A[128][32] and B[128][32] (8KB each); 2 chunks of 1KB per wave each
        gload_lds16(Ablk + (size_t)(c0 >> 2) * K + k0 + (c0 & 3) * 8, sA + wave * 512);
        gload_lds16(Ablk + (size_t)(c1 >> 2) * K + k0 + (c1 & 3) * 8, sA + 2048 + wave * 512);
        gload_lds16(Bblk + (size_t)(c0 >> 2) * K + k0 + (c0 & 3) * 8, sB + wave * 512);
        gload_lds16(Bblk + (size_t)(c1 >> 2) * K + k0 + (c1 & 3) * 8, sB + 2048 + wave * 512);
        __syncthreads();   // drains vmcnt -> staged data visible

        bf16x8 a[4], b[4];
#pragma unroll
        for (int i = 0; i < 4; i++)
            a[i] = *(const bf16x8*)(sA + (wm + i * 16 + r) * 32 + g * 8);
#pragma unroll
        for (int j = 0; j < 4; j++)
            b[j] = *(const bf16x8*)(sB + (wn + j * 16 + r) * 32 + g * 8);
#pragma unroll
        for (int i = 0; i < 4; i++)
#pragma unroll
            for (int j = 0; j < 4; j++)
                acc[i][j] = mfma16(a[i], b[j], acc[i][j]);
        __syncthreads();   // all reads done before next stage overwrites
    }

    // epilogue: D frag: col = r (+16j), row = g*4+rr (+16i)
#pragma unroll
    for (int j = 0; j < 4; j++) {
        int n = n0 + wn + j * 16 + r;
        float bv = bias[n];
#pragma unroll
        for (int i = 0; i < 4; i++) {
#pragma unroll
            for (int rr = 0; rr < 4; rr++) {
                int mrow = m0 + wm + i * 16 + g * 4 + rr;
                float val = acc[i][j][rr] + bv;
                if (RELU) val = fmaxf(val, 0.f);
                if (OUT_F32) Cf[(size_t)mrow * N + n] = val;
                if (OUT_BF16) Cb[(size_t)mrow * N + n] = (bf16_t)val;
            }
        }
    }
}

// ---------------------------------------------------------------------------
// Flash attention, swapped-QK^T structure.
// Qp,Kp [B*S][1024] bf16 (col = h*64+d), VT [B][H][64][S] bf16.
// grid (S/64, H, B), 256 threads = 4 waves; each wave owns 16 q-rows.
// Swapped QK: s = mfma(A=K-rows, B=Q-rows) -> lane(r,g) holds
//   E[kv = j*16 + g*4 + rr][q = r]  => softmax row-reduce is 15 in-lane ops
//   + 2 shfl_xor (across the 4 g-groups). No barriers (P tile is per-wave).
// P goes through a per-wave XOR-swizzled LDS tile (byte ^= (row&7)<<4) to
// become the PV A-operand; swizzle verified conflict-free on both sides.
// K-fragments double-buffered in registers; V issued right after QK so its
// L2 latency hides under softmax.
// ---------------------------------------------------------------------------
__device__ __forceinline__ void attn_tile(const bf16_t* __restrict__ Kb,
                                          const bf16_t* __restrict__ Vb,
                                          bf16_t* __restrict__ Pw,
                                          int kv0, int r, int g,
                                          bf16x8 (&ak)[4][2], bf16x8 (&akn)[4][2],
                                          const bf16x8 (&bq)[2],
                                          f32x4 (&o)[4], float& m_run, float& l_run) {
    // QK^T (swapped): s4[j][rr] = E[kv0 + j*16 + g*4 + rr][q0 + r]
    f32x4 s4[4];
#pragma unroll
    for (int j = 0; j < 4; j++) {
        f32x4 z; z[0] = z[1] = z[2] = z[3] = 0.f;
        z = mfma16(ak[j][0], bq[0], z);
        s4[j] = mfma16(ak[j][1], bq[1], z);
    }
    // issue V loads for this tile (consumed after softmax)
    bf16x8 bv[2][4];
#pragma unroll
    for (int kk = 0; kk < 2; kk++)
#pragma unroll
        for (int j = 0; j < 4; j++)
            bv[kk][j] = *(const bf16x8*)(Vb + (size_t)(j * 16 + r) * S_SZ + kv0 + kk * 32 + g * 8);
    // issue K loads for next tile (wrap on last; harmless)
    const int kvn = (kv0 + 64) & (S_SZ - 1);
#pragma unroll
    for (int j = 0; j < 4; j++)
#pragma unroll
        for (int kk = 0; kk < 2; kk++)
            akn[j][kk] = *(const bf16x8*)(Kb + (size_t)(kvn + j * 16 + r) * D_MODEL + kk * 32 + g * 8);

    // online softmax for q = r (raw-score domain; scale folded into exp arg)
    float mx = -1e30f;
#pragma unroll
    for (int j = 0; j < 4; j++)
#pragma unroll
        for (int rr = 0; rr < 4; rr++) mx = fmaxf(mx, s4[j][rr]);
    mx = fmaxf(mx, __shfl_xor(mx, 16));
    mx = fmaxf(mx, __shfl_xor(mx, 32));
    const float mnew = fmaxf(m_run, mx);
    const float mns = mnew * 0.125f;   // scale = 1/sqrt(64)
    float sum = 0.f;
#pragma unroll
    for (int j = 0; j < 4; j++)
#pragma unroll
        for (int rr = 0; rr < 4; rr++) {
            float e = __expf(__builtin_fmaf(s4[j][rr], 0.125f, -mns));
            s4[j][rr] = e;
            sum += e;
        }
    sum += __shfl_xor(sum, 16);
    sum += __shfl_xor(sum, 32);
    const float alpha = __expf(__builtin_fmaf(m_run, 0.125f, -mns));
    l_run = l_run * alpha + sum;
    m_run = mnew;
    // O-rescale: O rows live at q = g*4+rr; fetch that q's alpha from lane q
#pragma unroll
    for (int rr = 0; rr < 4; rr++) {
        float a_o = __shfl(alpha, g * 4 + rr);
#pragma unroll
        for (int j = 0; j < 4; j++) o[j][rr] *= a_o;
    }
    // P -> per-wave LDS tile [16 q][64 kv] bf16, XOR-swizzled rows
#pragma unroll
    for (int j = 0; j < 4; j++) {
        bf16x4 pw;
#pragma unroll
        for (int rr = 0; rr < 4; rr++) pw[rr] = (bf16_t)s4[j][rr];
        const int eoff = r * 64 + ((((j * 32 + g * 8)) ^ ((r & 7) << 4)) >> 1);
        *(bf16x4*)(Pw + eoff) = pw;
    }
    // PV: A = P rows q (from swizzled LDS), B = VT rows d
#pragma unroll
    for (int kk = 0; kk < 2; kk++) {
        const int eoff = r * 64 + ((((kk * 64 + g * 16)) ^ ((r & 7) << 4)) >> 1);
        bf16x8 ap = *(const bf16x8*)(Pw + eoff);
#pragma unroll
        for (int j = 0; j < 4; j++) o[j] = mfma16(ap, bv[kk][j], o[j]);
    }
}

__global__ __launch_bounds__(256) void flash_attn(const bf16_t* __restrict__ Qp,
                                                  const bf16_t* __restrict__ Kp,
                                                  const bf16_t* __restrict__ VT,
                                                  bf16_t* __restrict__ Oa) {
    __shared__ bf16_t sP[4][16 * 64];
    const int tid = threadIdx.x;
    const int lane = tid & 63, wave = tid >> 6;
    const int g = lane >> 4, r = lane & 15;
    const int h = blockIdx.y, b = blockIdx.z;
    const int q0 = blockIdx.x * 64 + wave * 16;

    const bf16_t* Qb = Qp + (size_t)b * S_SZ * D_MODEL + h * HEAD_DIM;
    const bf16_t* Kb = Kp + (size_t)b * S_SZ * D_MODEL + h * HEAD_DIM;
    const bf16_t* Vb = VT + ((size_t)(b * NUM_HEADS + h) * HEAD_DIM) * S_SZ;
    bf16_t* Pw = sP[wave];

    // Q as B-operand: lane(r,g) holds Q[q0+r][k = kk*32 + g*8 + 0..7]
    bf16x8 bq[2];
    bq[0] = *(const bf16x8*)(Qb + (size_t)(q0 + r) * D_MODEL + g * 8);
    bq[1] = *(const bf16x8*)(Qb + (size_t)(q0 + r) * D_MODEL + 32 + g * 8);

    float m_run = -1e30f, l_run = 0.f;
    f32x4 o[4];
#pragma unroll
    for (int j = 0; j < 4; j++)
#pragma unroll
        for (int e = 0; e < 4; e++) o[j][e] = 0.f;

    // prologue: K fragments for tile 0
    bf16x8 akA[4][2], akB[4][2];
#pragma unroll
    for (int j = 0; j < 4; j++)
#pragma unroll
        for (int kk = 0; kk < 2; kk++)
            akA[j][kk] = *(const bf16x8*)(Kb + (size_t)(j * 16 + r) * D_MODEL + kk * 32 + g * 8);

    for (int kv0 = 0; kv0 < S_SZ; kv0 += 128) {
        attn_tile(Kb, Vb, Pw, kv0,      r, g, akA, akB, bq, o, m_run, l_run);
        attn_tile(Kb, Vb, Pw, kv0 + 64, r, g, akB, akA, bq, o, m_run, l_run);
    }

    // normalize + write: O[q = q0+g*4+rr][d = j*16+r]
    float l_o[4];
#pragma unroll
    for (int rr = 0; rr < 4; rr++) l_o[rr] = __shfl(l_run, g * 4 + rr);
#pragma unroll
    for (int j = 0; j < 4; j++) {
#pragma unroll
        for (int rr = 0; rr < 4; rr++) {
            float val = o[j][rr] / l_o[rr];
            Oa[((size_t)b * S_SZ + q0 + g * 4 + rr) * D_MODEL + h * HEAD_DIM + j * 16 + r] = (bf16_t)val;
        }
    }
}

// ---------------------------------------------------------------------------
// LayerNorm over 1024, fused residual add. 1 block = 1 row, 256 threads x4.
// ---------------------------------------------------------------------------
__global__ __launch_bounds__(256) void ln_fused(const float* __restrict__ A,
                                                const float* __restrict__ R,
                                                const float* __restrict__ gamma,
                                                const float* __restrict__ beta,
                                                float* __restrict__ Xf,
                                                bf16_t* __restrict__ Xb) {
    __shared__ float red[8];
    int row = blockIdx.x, tid = threadIdx.x;
    size_t base = (size_t)row * D_MODEL + tid * 4;
    float4 a = *(const float4*)(A + base);
    float4 rv = *(const float4*)(R + base);
    float v0 = a.x + rv.x, v1 = a.y + rv.y, v2 = a.z + rv.z, v3 = a.w + rv.w;
    float s = v0 + v1 + v2 + v3;
    float q = v0 * v0 + v1 * v1 + v2 * v2 + v3 * v3;
#pragma unroll
    for (int off = 32; off; off >>= 1) { s += __shfl_down(s, off); q += __shfl_down(q, off); }
    if ((tid & 63) == 0) { red[tid >> 6] = s; red[4 + (tid >> 6)] = q; }
    __syncthreads();
    s = red[0] + red[1] + red[2] + red[3];
    q = red[4] + red[5] + red[6] + red[7];
    float mean = s * (1.f / D_MODEL);
    float var = q * (1.f / D_MODEL) - mean * mean;
    float rstd = rsqrtf(var + 1e-5f);
    float4 gm = *(const float4*)(gamma + tid * 4);
    float4 bt = *(const float4*)(beta + tid * 4);
    float y0 = (v0 - mean) * rstd * gm.x + bt.x;
    float y1 = (v1 - mean) * rstd * gm.y + bt.y;
    float y2 = (v2 - mean) * rstd * gm.z + bt.z;
    float y3 = (v3 - mean) * rstd * gm.w + bt.w;
    float4 yo; yo.x = y0; yo.y = y1; yo.z = y2; yo.w = y3;
    *(float4*)(Xf + base) = yo;
    if (Xb) {
        bf16x4 ob; ob[0] = (bf16_t)y0; ob[1] = (bf16_t)y1; ob[2] = (bf16_t)y2; ob[3] = (bf16_t)y3;
        *(bf16x4*)(Xb + base) = ob;
    }
}

// ---------------------------------------------------------------------------
extern "C" void kernel_launch(void* const* d_in, const int* in_sizes, int n_in,
                              void* d_out, int out_size, void* d_ws, size_t ws_size,
                              hipStream_t stream) {
    const float* value = (const float*)d_in[0];
    const float* key   = (const float*)d_in[1];
    const float* query = (const float*)d_in[2];
    const float* wq = (const float*)d_in[3];
    const float* bq = (const float*)d_in[4];
    const float* wk = (const float*)d_in[5];
    const float* bk = (const float*)d_in[6];
    const float* wv = (const float*)d_in[7];
    const float* bv = (const float*)d_in[8];
    const float* wo = (const float*)d_in[9];
    const float* bo = (const float*)d_in[10];
    const float* g1 = (const float*)d_in[11];
    const float* beta1 = (const float*)d_in[12];
    const float* w1 = (const float*)d_in[13];
    const float* b1 = (const float*)d_in[14];
    const float* w2 = (const float*)d_in[15];
    const float* b2 = (const float*)d_in[16];
    const float* g2 = (const float*)d_in[17];
    const float* beta2 = (const float*)d_in[18];
    (void)in_sizes; (void)n_in; (void)out_size; (void)ws_size;

    const size_t MB = 1ull << 20;
    char* ws = (char*)d_ws;
    bf16_t* wqT = (bf16_t*)(ws + 0 * MB);   // [1024][1024]
    bf16_t* wkT = (bf16_t*)(ws + 2 * MB);
    bf16_t* wvT = (bf16_t*)(ws + 4 * MB);
    bf16_t* woT = (bf16_t*)(ws + 6 * MB);
    bf16_t* w1T = (bf16_t*)(ws + 8 * MB);   // [4096][1024]
    bf16_t* w2T = (bf16_t*)(ws + 16 * MB);  // [1024][4096]
    bf16_t* q_bf = (bf16_t*)(ws + 24 * MB); // [4096][1024]
    bf16_t* k_bf = (bf16_t*)(ws + 32 * MB);
    bf16_t* v_bf = (bf16_t*)(ws + 40 * MB);
    bf16_t* Qp  = (bf16_t*)(ws + 48 * MB);
    bf16_t* Kp  = (bf16_t*)(ws + 56 * MB);
    bf16_t* Vp  = (bf16_t*)(ws + 64 * MB);
    bf16_t* VT  = (bf16_t*)(ws + 72 * MB);  // [B][H][64][S]
    bf16_t* attn = (bf16_t*)(ws + 24 * MB); // reuse q_bf
    float*  attn_out = (float*)(ws + 80 * MB); // [4096][1024] f32
    float*  x_f = (float*)(ws + 96 * MB);
    bf16_t* x_b = (bf16_t*)(ws + 112 * MB);
    bf16_t* h_b = (bf16_t*)(ws + 40 * MB);  // [4096][4096] bf16, reuse v_bf..Vp
    float*  y_f = (float*)(ws + 80 * MB);   // reuse attn_out

    dim3 blk(256);

    // 1) casts + weight transposes
    cast_f32_bf16<<<4096, blk, 0, stream>>>(query, q_bf);
    cast_f32_bf16<<<4096, blk, 0, stream>>>(key, k_bf);
    cast_f32_bf16<<<4096, blk, 0, stream>>>(value, v_bf);
    transpose_cast_w<<<dim3(32, 32), blk, 0, stream>>>(wq, wqT, 1024, 1024);
    transpose_cast_w<<<dim3(32, 32), blk, 0, stream>>>(wk, wkT, 1024, 1024);
    transpose_cast_w<<<dim3(32, 32), blk, 0, stream>>>(wv, wvT, 1024, 1024);
    transpose_cast_w<<<dim3(32, 32), blk, 0, stream>>>(wo, woT, 1024, 1024);
    transpose_cast_w<<<dim3(32, 128), blk, 0, stream>>>(w1, w1T, 1024, 4096);
    transpose_cast_w<<<dim3(128, 32), blk, 0, stream>>>(w2, w2T, 4096, 1024);

    // 2) QKV projections (bf16 out)
    gemm_bt<false, true, false><<<dim3(32, 8), blk, 0, stream>>>(q_bf, wqT, bq, nullptr, Qp, M_ROWS, D_MODEL, D_MODEL);
    gemm_bt<false, true, false><<<dim3(32, 8), blk, 0, stream>>>(k_bf, wkT, bk, nullptr, Kp, M_ROWS, D_MODEL, D_MODEL);
    gemm_bt<false, true, false><<<dim3(32, 8), blk, 0, stream>>>(v_bf, wvT, bv, nullptr, Vp, M_ROWS, D_MODEL, D_MODEL);

    // 3) V transpose for PV B-operand
    transpose_v<<<dim3(64, 2, 32), blk, 0, stream>>>(Vp, VT);

    // 4) flash attention
    flash_attn<<<dim3(32, 16, 2), blk, 0, stream>>>(Qp, Kp, VT, attn);

    // 5) WO projection (f32 out)
    gemm_bt<false, false, true><<<dim3(32, 8), blk, 0, stream>>>(attn, woT, bo, attn_out, nullptr, M_ROWS, D_MODEL, D_MODEL);

    // 6) LN1: x = LN(attn_out + query)
    ln_fused<<<4096, blk, 0, stream>>>(attn_out, query, g1, beta1, x_f, x_b);

    // 7) FF1 + ReLU (bf16 out)
    gemm_bt<true, true, false><<<dim3(32, 32), blk, 0, stream>>>(x_b, w1T, b1, nullptr, h_b, M_ROWS, FF_DIM, D_MODEL);

    // 8) FF2 (f32 out)
    gemm_bt<false, false, true><<<dim3(32, 8), blk, 0, stream>>>(h_b, w2T, b2, y_f, nullptr, M_ROWS, D_MODEL, FF_DIM);

    // 9) LN2 -> d_out
    ln_fused<<<4096, blk, 0, stream>>>(y_f, x_f, g2, beta2, (float*)d_out, nullptr);
}

// Round 3
// 430.810 us; speedup vs baseline: 1.3898x; 1.3840x over previous
//
#include <hip/hip_runtime.h>
#include <hip/hip_bf16.h>
#include <cstdint>

typedef __bf16 bf16_t;
typedef __attribute__((ext_vector_type(2))) __bf16 bf16x2;
typedef __attribute__((ext_vector_type(4))) __bf16 bf16x4;
typedef __attribute__((ext_vector_type(8))) __bf16 bf16x8;
typedef __attribute__((ext_vector_type(4))) float f32x4;
typedef __attribute__((ext_vector_type(16))) float f32x16;
typedef __attribute__((ext_vector_type(2))) int int2v;
typedef __attribute__((ext_vector_type(4))) int int4v;

#define B_SZ 2
#define S_SZ 2048
#define D_MODEL 1024
#define NUM_HEADS 16
#define HEAD_DIM 64
#define FF_DIM 4096
#define M_ROWS (B_SZ * S_SZ)   // 4096

// ---------------------------------------------------------------------------
// async global->LDS (16B per lane, wave-uniform LDS base + lane*16)
// ---------------------------------------------------------------------------
__device__ __forceinline__ void gload_lds16(const void* g, void* lds) {
    __builtin_amdgcn_global_load_lds(
        (const __attribute__((address_space(1))) void*)(uintptr_t)g,
        (__attribute__((address_space(3))) void*)(uint32_t)(uintptr_t)lds,
        16, 0, 0);
}

__device__ __forceinline__ f32x4 mfma16(bf16x8 a, bf16x8 b, f32x4 c) {
    return __builtin_amdgcn_mfma_f32_16x16x32_bf16(a, b, c, 0, 0, 0);
}
__device__ __forceinline__ f32x16 mfma32(bf16x8 a, bf16x8 b, f32x16 c) {
    return __builtin_amdgcn_mfma_f32_32x32x16_bf16(a, b, c, 0, 0, 0);
}
// VALU cross-half exchange: returns {[a.lo|b.lo], [a.hi|b.hi]}
__device__ __forceinline__ int2v plswap(int a, int b) {
    return __builtin_amdgcn_permlane32_swap(a, b, false, false);
}
__device__ __forceinline__ int packbf(float a, float b) {
    bf16x2 t; t[0] = (bf16_t)a; t[1] = (bf16_t)b;
    return __builtin_bit_cast(int, t);
}

// ---------------------------------------------------------------------------
// elementwise cast f32 -> bf16 (4 elems/thread)
// ---------------------------------------------------------------------------
__global__ __launch_bounds__(256) void cast_f32_bf16(const float* __restrict__ in,
                                                     bf16_t* __restrict__ out) {
    size_t i = ((size_t)blockIdx.x * 256 + threadIdx.x) * 4;
    float4 v = *(const float4*)(in + i);
    bf16x4 o;
    o[0] = (bf16_t)v.x; o[1] = (bf16_t)v.y; o[2] = (bf16_t)v.z; o[3] = (bf16_t)v.w;
    *(bf16x4*)(out + i) = o;
}

// ---------------------------------------------------------------------------
// W [K][N] f32  ->  WT [N][K] bf16   (32x32 tiles)
// ---------------------------------------------------------------------------
__global__ __launch_bounds__(256) void transpose_cast_w(const float* __restrict__ W,
                                                        bf16_t* __restrict__ WT,
                                                        int K, int N) {
    __shared__ float t[32][33];
    int tid = threadIdx.x;
    int rr = tid >> 3, cc = (tid & 7) * 4;
    int k0 = blockIdx.x * 32, n0 = blockIdx.y * 32;
    float4 v = *(const float4*)(W + (size_t)(k0 + rr) * N + n0 + cc);
    t[rr][cc + 0] = v.x; t[rr][cc + 1] = v.y; t[rr][cc + 2] = v.z; t[rr][cc + 3] = v.w;
    __syncthreads();
    bf16x4 o;
    o[0] = (bf16_t)t[cc + 0][rr]; o[1] = (bf16_t)t[cc + 1][rr];
    o[2] = (bf16_t)t[cc + 2][rr]; o[3] = (bf16_t)t[cc + 3][rr];
    *(bf16x4*)(WT + (size_t)(n0 + rr) * K + k0 + cc) = o;
}

// ---------------------------------------------------------------------------
// Vp [B*S][1024] bf16 -> VT [B][H][64][S] bf16
// grid: (S/32, 2, B*H)
// ---------------------------------------------------------------------------
__global__ __launch_bounds__(256) void transpose_v(const bf16_t* __restrict__ Vp,
                                                   bf16_t* __restrict__ VT) {
    __shared__ bf16_t t[32][34];
    int tid = threadIdx.x;
    int rr = tid >> 3, cc = (tid & 7) * 4;
    int bh = blockIdx.z;            // b*16+h
    int b = bh >> 4, h = bh & 15;
    int s0 = blockIdx.x * 32, d0 = blockIdx.y * 32;
    bf16x4 v = *(const bf16x4*)(Vp + ((size_t)(b * S_SZ + s0 + rr)) * D_MODEL + h * HEAD_DIM + d0 + cc);
    t[rr][cc + 0] = v[0]; t[rr][cc + 1] = v[1]; t[rr][cc + 2] = v[2]; t[rr][cc + 3] = v[3];
    __syncthreads();
    bf16x4 o;
    o[0] = t[cc + 0][rr]; o[1] = t[cc + 1][rr]; o[2] = t[cc + 2][rr]; o[3] = t[cc + 3][rr];
    *(bf16x4*)(VT + ((size_t)(bh * HEAD_DIM + d0 + rr)) * S_SZ + s0 + cc) = o;
}

// ---------------------------------------------------------------------------
// GEMM: C[M][N] = A[M][K] @ Bt[N][K]^T + bias  (A,Bt bf16; acc fp32)
// 128x128 tile, BK=32, 4 waves (each 64x64 = 4x4 frags of 16x16x32)
// ---------------------------------------------------------------------------
template<bool RELU, bool OUT_BF16, bool OUT_F32>
__global__ __launch_bounds__(256) void gemm_bt(const bf16_t* __restrict__ A,
                                               const bf16_t* __restrict__ Bt,
                                               const float* __restrict__ bias,
                                               float* __restrict__ Cf,
                                               bf16_t* __restrict__ Cb,
                                               int M, int N, int K) {
    __shared__ bf16_t sA[128 * 32];
    __shared__ bf16_t sB[128 * 32];
    const int tid = threadIdx.x;
    const int lane = tid & 63, wave = tid >> 6;
    const int g = lane >> 4, r = lane & 15;
    const int m0 = blockIdx.x * 128, n0 = blockIdx.y * 128;
    const int wm = (wave >> 1) * 64, wn = (wave & 1) * 64;

    const bf16_t* Ablk = A + (size_t)m0 * K;
    const bf16_t* Bblk = Bt + (size_t)n0 * K;
    const int c0 = wave * 64 + lane;   // chunk 0..255
    const int c1 = c0 + 256;           // chunk 256..511

    f32x4 acc[4][4];
#pragma unroll
    for (int i = 0; i < 4; i++)
#pragma unroll
        for (int j = 0; j < 4; j++)
#pragma unroll
            for (int e = 0; e < 4; e++) acc[i][j][e] = 0.f;

    for (int k0 = 0; k0 < K; k0 += 32) {
        gload_lds16(Ablk + (size_t)(c0 >> 2) * K + k0 + (c0 & 3) * 8, sA + wave * 512);
        gload_lds16(Ablk + (size_t)(c1 >> 2) * K + k0 + (c1 & 3) * 8, sA + 2048 + wave * 512);
        gload_lds16(Bblk + (size_t)(c0 >> 2) * K + k0 + (c0 & 3) * 8, sB + wave * 512);
        gload_lds16(Bblk + (size_t)(c1 >> 2) * K + k0 + (c1 & 3) * 8, sB + 2048 + wave * 512);
        __syncthreads();

        bf16x8 a[4], b[4];
#pragma unroll
        for (int i = 0; i < 4; i++)
            a[i] = *(const bf16x8*)(sA + (wm + i * 16 + r) * 32 + g * 8);
#pragma unroll
        for (int j = 0; j < 4; j++)
            b[j] = *(const bf16x8*)(sB + (wn + j * 16 + r) * 32 + g * 8);
#pragma unroll
        for (int i = 0; i < 4; i++)
#pragma unroll
            for (int j = 0; j < 4; j++)
                acc[i][j] = mfma16(a[i], b[j], acc[i][j]);
        __syncthreads();
    }

#pragma unroll
    for (int j = 0; j < 4; j++) {
        int n = n0 + wn + j * 16 + r;
        float bv = bias[n];
#pragma unroll
        for (int i = 0; i < 4; i++) {
#pragma unroll
            for (int rr = 0; rr < 4; rr++) {
                int mrow = m0 + wm + i * 16 + g * 4 + rr;
                float val = acc[i][j][rr] + bv;
                if (RELU) val = fmaxf(val, 0.f);
                if (OUT_F32) Cf[(size_t)mrow * N + n] = val;
                if (OUT_BF16) Cb[(size_t)mrow * N + n] = (bf16_t)val;
            }
        }
    }
}

// ---------------------------------------------------------------------------
// Flash attention, 32x32 double-swapped, zero ds-ops in the main loop.
// QK:  S^T = mfma32(A=K[kv][d], B=Q^T)   -> lane owns q = lane&31, 16 kv rows
// PV:  O^T = mfma32(A=V^T[d][kv], B=P)   -> lane owns q = lane&31, d rows
// Softmax entirely per-lane + permlane32_swap (VALU). alpha/l in-lane.
// Split-KV: 4 waves = 2 q-tiles x 2 kv-halves; merge via LDS at the end.
// Grid (S/64, H, B), 256 threads.
// ---------------------------------------------------------------------------
__device__ __forceinline__ void attn_tile32(
    const bf16_t* __restrict__ Kb, const bf16_t* __restrict__ Vb,
    int l31, int hi, int kvn,
    const bf16x8 (&bq)[4],
    bf16x8 (&ak)[4], bf16x8 (&av)[4],
    bf16x8 (&akn)[4], bf16x8 (&avn)[4],
    f32x16& o0, f32x16& o1, float& m_run, float& l_run)
{
    // QK^T (swapped): s reg e -> E[kv = (e&3)+8*(e>>2)+4*hi][q = l31]
    f32x16 s;
#pragma unroll
    for (int e = 0; e < 16; e++) s[e] = 0.f;
#pragma unroll
    for (int kb = 0; kb < 4; kb++) s = mfma32(ak[kb], bq[kb], s);

    // prefetch next tile's K and V fragments (consumed next call)
#pragma unroll
    for (int kb = 0; kb < 4; kb++)
        akn[kb] = *(const bf16x8*)(Kb + (size_t)(kvn + l31) * D_MODEL + kb * 16 + hi * 8);
#pragma unroll
    for (int db = 0; db < 2; db++)
#pragma unroll
        for (int kb = 0; kb < 2; kb++)
            avn[db * 2 + kb] = *(const bf16x8*)(Vb + (size_t)(db * 32 + l31) * S_SZ + kvn + kb * 16 + hi * 8);

    // row max: 15 in-lane + 1 permlane swap (VALU)
    float ma = fmaxf(fmaxf(s[0], s[1]), fmaxf(s[2], s[3]));
    float mb = fmaxf(fmaxf(s[4], s[5]), fmaxf(s[6], s[7]));
    float mc = fmaxf(fmaxf(s[8], s[9]), fmaxf(s[10], s[11]));
    float md = fmaxf(fmaxf(s[12], s[13]), fmaxf(s[14], s[15]));
    float mx = fmaxf(fmaxf(ma, mb), fmaxf(mc, md));
    int2v pr = plswap(__float_as_int(mx), __float_as_int(mx));
    mx = fmaxf(__int_as_float(pr[0]), __int_as_float(pr[1]));

    const float mnew = fmaxf(m_run, mx);
    const float mns = mnew * 0.125f;          // scale = 1/sqrt(64)
#pragma unroll
    for (int e = 0; e < 16; e++) s[e] = __expf(__builtin_fmaf(s[e], 0.125f, -mns));
    float t0 = (s[0] + s[1]) + (s[2] + s[3]);
    float t1 = (s[4] + s[5]) + (s[6] + s[7]);
    float t2 = (s[8] + s[9]) + (s[10] + s[11]);
    float t3 = (s[12] + s[13]) + (s[14] + s[15]);
    float sum = (t0 + t1) + (t2 + t3);
    int2v sp = plswap(__float_as_int(sum), __float_as_int(sum));
    sum = __int_as_float(sp[0]) + __int_as_float(sp[1]);

    const float alpha = __expf(__builtin_fmaf(m_run, 0.125f, -mns));
    m_run = mnew;
    l_run = l_run * alpha + sum;
#pragma unroll
    for (int e = 0; e < 16; e++) { o0[e] *= alpha; o1[e] *= alpha; }

    // pack P -> bf16 B-frags via permlane32_swap; PV
#pragma unroll
    for (int kb2 = 0; kb2 < 2; kb2++) {
        const int bse = kb2 * 8;
        int W0 = packbf(s[bse + 0], s[bse + 1]);
        int W1 = packbf(s[bse + 2], s[bse + 3]);
        int W2 = packbf(s[bse + 4], s[bse + 5]);
        int W3 = packbf(s[bse + 6], s[bse + 7]);
        int2v r02 = plswap(W0, W2);
        int2v r13 = plswap(W1, W3);
        int4v fw; fw[0] = r02[0]; fw[1] = r13[0]; fw[2] = r02[1]; fw[3] = r13[1];
        bf16x8 pf = __builtin_bit_cast(bf16x8, fw);
        o0 = mfma32(av[kb2], pf, o0);
        o1 = mfma32(av[2 + kb2], pf, o1);
    }
}

__global__ __launch_bounds__(256) void flash_attn(const bf16_t* __restrict__ Qp,
                                                  const bf16_t* __restrict__ Kp,
                                                  const bf16_t* __restrict__ VT,
                                                  bf16_t* __restrict__ Oa) {
    __shared__ float obuf[32][2][64];   // [o-word][qt][lane] - conflict-free
    __shared__ float mrg[2][64][2];     // [qt][lane][m,l]
    const int tid = threadIdx.x;
    const int lane = tid & 63;
    const int wave = tid >> 6;
    const int qt = wave >> 1, half = wave & 1;
    const int l31 = lane & 31, hi = lane >> 5;
    const int h = blockIdx.y, b = blockIdx.z;
    const int q0 = blockIdx.x * 64 + qt * 32;
    const int kvbase = half * (S_SZ / 2);

    const bf16_t* Qb = Qp + (size_t)b * S_SZ * D_MODEL + h * HEAD_DIM;
    const bf16_t* Kb = Kp + (size_t)b * S_SZ * D_MODEL + h * HEAD_DIM;
    const bf16_t* Vb = VT + ((size_t)(b * NUM_HEADS + h) * HEAD_DIM) * S_SZ;

    // Q B-frags: lane holds Q[q0+l31][d = kb*16 + hi*8 + e]
    bf16x8 bq[4];
#pragma unroll
    for (int kb = 0; kb < 4; kb++)
        bq[kb] = *(const bf16x8*)(Qb + (size_t)(q0 + l31) * D_MODEL + kb * 16 + hi * 8);

    f32x16 o0, o1;
#pragma unroll
    for (int e = 0; e < 16; e++) { o0[e] = 0.f; o1[e] = 0.f; }
    float m_run = -1e30f, l_run = 0.f;

    // prologue: tile 0 fragments
    bf16x8 akA[4], akB[4], avA[4], avB[4];
#pragma unroll
    for (int kb = 0; kb < 4; kb++)
        akA[kb] = *(const bf16x8*)(Kb + (size_t)(kvbase + l31) * D_MODEL + kb * 16 + hi * 8);
#pragma unroll
    for (int db = 0; db < 2; db++)
#pragma unroll
        for (int kb = 0; kb < 2; kb++)
            avA[db * 2 + kb] = *(const bf16x8*)(Vb + (size_t)(db * 32 + l31) * S_SZ + kvbase + kb * 16 + hi * 8);

    for (int t = 0; t < 32; t += 2) {
        const int kv0 = kvbase + t * 32;
        attn_tile32(Kb, Vb, l31, hi, kv0 + 32, bq, akA, avA, akB, avB, o0, o1, m_run, l_run);
        const int kvn2 = (t + 2 < 32) ? kv0 + 64 : kvbase;   // wrap: valid dummy
        attn_tile32(Kb, Vb, l31, hi, kvn2, bq, akB, avB, akA, avA, o0, o1, m_run, l_run);
    }

    // split-KV merge: half==1 publishes partials, half==0 combines + stores
    if (half == 1) {
        mrg[qt][lane][0] = m_run;
        mrg[qt][lane][1] = l_run;
#pragma unroll
        for (int e = 0; e < 16; e++) {
            obuf[e][qt][lane] = o0[e];
            obuf[16 + e][qt][lane] = o1[e];
        }
    }
    __syncthreads();
    if (half == 0) {
        const float m2 = mrg[qt][lane][0], l2 = mrg[qt][lane][1];
        const float mm = fmaxf(m_run, m2);
        const float e1 = __expf((m_run - mm) * 0.125f);
        const float e2 = __expf((m2 - mm) * 0.125f);
        const float linv = 1.f / (l_run * e1 + l2 * e2);
        bf16_t* Orow = Oa + ((size_t)b * S_SZ + q0 + l31) * D_MODEL + h * HEAD_DIM;
#pragma unroll
        for (int db = 0; db < 2; db++) {
#pragma unroll
            for (int rq = 0; rq < 4; rq++) {
                bf16x4 st;
#pragma unroll
                for (int i = 0; i < 4; i++) {
                    const int e = rq * 4 + i;
                    const float own = db ? o1[e] : o0[e];
                    const float oth = obuf[db * 16 + e][qt][lane];
                    st[i] = (bf16_t)((own * e1 + oth * e2) * linv);
                }
                *(bf16x4*)(Orow + db * 32 + rq * 8 + hi * 4) = st;
            }
        }
    }
}

// ---------------------------------------------------------------------------
// LayerNorm over 1024, fused residual add. 1 block = 1 row, 256 threads x4.
// ---------------------------------------------------------------------------
__global__ __launch_bounds__(256) void ln_fused(const float* __restrict__ A,
                                                const float* __restrict__ R,
                                                const float* __restrict__ gamma,
                                                const float* __restrict__ beta,
                                                float* __restrict__ Xf,
                                                bf16_t* __restrict__ Xb) {
    __shared__ float red[8];
    int row = blockIdx.x, tid = threadIdx.x;
    size_t base = (size_t)row * D_MODEL + tid * 4;
    float4 a = *(const float4*)(A + base);
    float4 rv = *(const float4*)(R + base);
    float v0 = a.x + rv.x, v1 = a.y + rv.y, v2 = a.z + rv.z, v3 = a.w + rv.w;
    float s = v0 + v1 + v2 + v3;
    float q = v0 * v0 + v1 * v1 + v2 * v2 + v3 * v3;
#pragma unroll
    for (int off = 32; off; off >>= 1) { s += __shfl_down(s, off); q += __shfl_down(q, off); }
    if ((tid & 63) == 0) { red[tid >> 6] = s; red[4 + (tid >> 6)] = q; }
    __syncthreads();
    s = red[0] + red[1] + red[2] + red[3];
    q = red[4] + red[5] + red[6] + red[7];
    float mean = s * (1.f / D_MODEL);
    float var = q * (1.f / D_MODEL) - mean * mean;
    float rstd = rsqrtf(var + 1e-5f);
    float4 gm = *(const float4*)(gamma + tid * 4);
    float4 bt = *(const float4*)(beta + tid * 4);
    float y0 = (v0 - mean) * rstd * gm.x + bt.x;
    float y1 = (v1 - mean) * rstd * gm.y + bt.y;
    float y2 = (v2 - mean) * rstd * gm.z + bt.z;
    float y3 = (v3 - mean) * rstd * gm.w + bt.w;
    float4 yo; yo.x = y0; yo.y = y1; yo.z = y2; yo.w = y3;
    *(float4*)(Xf + base) = yo;
    if (Xb) {
        bf16x4 ob; ob[0] = (bf16_t)y0; ob[1] = (bf16_t)y1; ob[2] = (bf16_t)y2; ob[3] = (bf16_t)y3;
        *(bf16x4*)(Xb + base) = ob;
    }
}

// ---------------------------------------------------------------------------
extern "C" void kernel_launch(void* const* d_in, const int* in_sizes, int n_in,
                              void* d_out, int out_size, void* d_ws, size_t ws_size,
                              hipStream_t stream) {
    const float* value = (const float*)d_in[0];
    const float* key   = (const float*)d_in[1];
    const float* query = (const float*)d_in[2];
    const float* wq = (const float*)d_in[3];
    const float* bq = (const float*)d_in[4];
    const float* wk = (const float*)d_in[5];
    const float* bk = (const float*)d_in[6];
    const float* wv = (const float*)d_in[7];
    const float* bv = (const float*)d_in[8];
    const float* wo = (const float*)d_in[9];
    const float* bo = (const float*)d_in[10];
    const float* g1 = (const float*)d_in[11];
    const float* beta1 = (const float*)d_in[12];
    const float* w1 = (const float*)d_in[13];
    const float* b1 = (const float*)d_in[14];
    const float* w2 = (const float*)d_in[15];
    const float* b2 = (const float*)d_in[16];
    const float* g2 = (const float*)d_in[17];
    const float* beta2 = (const float*)d_in[18];
    (void)in_sizes; (void)n_in; (void)out_size; (void)ws_size;

    const size_t MB = 1ull << 20;
    char* ws = (char*)d_ws;
    bf16_t* wqT = (bf16_t*)(ws + 0 * MB);   // [1024][1024]
    bf16_t* wkT = (bf16_t*)(ws + 2 * MB);
    bf16_t* wvT = (bf16_t*)(ws + 4 * MB);
    bf16_t* woT = (bf16_t*)(ws + 6 * MB);
    bf16_t* w1T = (bf16_t*)(ws + 8 * MB);   // [4096][1024]
    bf16_t* w2T = (bf16_t*)(ws + 16 * MB);  // [1024][4096]
    bf16_t* q_bf = (bf16_t*)(ws + 24 * MB); // [4096][1024]
    bf16_t* k_bf = (bf16_t*)(ws + 32 * MB);
    bf16_t* v_bf = (bf16_t*)(ws + 40 * MB);
    bf16_t* Qp  = (bf16_t*)(ws + 48 * MB);
    bf16_t* Kp  = (bf16_t*)(ws + 56 * MB);
    bf16_t* Vp  = (bf16_t*)(ws + 64 * MB);
    bf16_t* VT  = (bf16_t*)(ws + 72 * MB);  // [B][H][64][S]
    bf16_t* attn = (bf16_t*)(ws + 24 * MB); // reuse q_bf
    float*  attn_out = (float*)(ws + 80 * MB); // [4096][1024] f32
    float*  x_f = (float*)(ws + 96 * MB);
    bf16_t* x_b = (bf16_t*)(ws + 112 * MB);
    bf16_t* h_b = (bf16_t*)(ws + 40 * MB);  // [4096][4096] bf16, reuse v_bf..Vp
    float*  y_f = (float*)(ws + 80 * MB);   // reuse attn_out

    dim3 blk(256);

    // 1) casts + weight transposes
    cast_f32_bf16<<<4096, blk, 0, stream>>>(query, q_bf);
    cast_f32_bf16<<<4096, blk, 0, stream>>>(key, k_bf);
    cast_f32_bf16<<<4096, blk, 0, stream>>>(value, v_bf);
    transpose_cast_w<<<dim3(32, 32), blk, 0, stream>>>(wq, wqT, 1024, 1024);
    transpose_cast_w<<<dim3(32, 32), blk, 0, stream>>>(wk, wkT, 1024, 1024);
    transpose_cast_w<<<dim3(32, 32), blk, 0, stream>>>(wv, wvT, 1024, 1024);
    transpose_cast_w<<<dim3(32, 32), blk, 0, stream>>>(wo, woT, 1024, 1024);
    transpose_cast_w<<<dim3(32, 128), blk, 0, stream>>>(w1, w1T, 1024, 4096);
    transpose_cast_w<<<dim3(128, 32), blk, 0, stream>>>(w2, w2T, 4096, 1024);

    // 2) QKV projections (bf16 out)
    gemm_bt<false, true, false><<<dim3(32, 8), blk, 0, stream>>>(q_bf, wqT, bq, nullptr, Qp, M_ROWS, D_MODEL, D_MODEL);
    gemm_bt<false, true, false><<<dim3(32, 8), blk, 0, stream>>>(k_bf, wkT, bk, nullptr, Kp, M_ROWS, D_MODEL, D_MODEL);
    gemm_bt<false, true, false><<<dim3(32, 8), blk, 0, stream>>>(v_bf, wvT, bv, nullptr, Vp, M_ROWS, D_MODEL, D_MODEL);

    // 3) V transpose for PV A-operand
    transpose_v<<<dim3(64, 2, 32), blk, 0, stream>>>(Vp, VT);

    // 4) flash attention
    flash_attn<<<dim3(32, 16, 2), blk, 0, stream>>>(Qp, Kp, VT, attn);

    // 5) WO projection (f32 out)
    gemm_bt<false, false, true><<<dim3(32, 8), blk, 0, stream>>>(attn, woT, bo, attn_out, nullptr, M_ROWS, D_MODEL, D_MODEL);

    // 6) LN1: x = LN(attn_out + query)
    ln_fused<<<4096, blk, 0, stream>>>(attn_out, query, g1, beta1, x_f, x_b);

    // 7) FF1 + ReLU (bf16 out)
    gemm_bt<true, true, false><<<dim3(32, 32), blk, 0, stream>>>(x_b, w1T, b1, nullptr, h_b, M_ROWS, FF_DIM, D_MODEL);

    // 8) FF2 (f32 out)
    gemm_bt<false, false, true><<<dim3(32, 8), blk, 0, stream>>>(h_b, w2T, b2, y_f, nullptr, M_ROWS, D_MODEL, FF_DIM);

    // 9) LN2 -> d_out
    ln_fused<<<4096, blk, 0, stream>>>(y_f, x_f, g2, beta2, (float*)d_out, nullptr);
}

// Round 4
// 402.130 us; speedup vs baseline: 1.4889x; 1.0713x over previous
//
#include <hip/hip_runtime.h>
#include <hip/hip_bf16.h>
#include <cstdint>
#include <math.h>

typedef __bf16 bf16_t;
typedef __attribute__((ext_vector_type(2))) __bf16 bf16x2;
typedef __attribute__((ext_vector_type(4))) __bf16 bf16x4;
typedef __attribute__((ext_vector_type(8))) __bf16 bf16x8;
typedef __attribute__((ext_vector_type(4))) float f32x4;
typedef __attribute__((ext_vector_type(16))) float f32x16;
typedef __attribute__((ext_vector_type(2))) int int2v;
typedef __attribute__((ext_vector_type(4))) int int4v;

#define B_SZ 2
#define S_SZ 2048
#define D_MODEL 1024
#define NUM_HEADS 16
#define HEAD_DIM 64
#define FF_DIM 4096
#define M_ROWS (B_SZ * S_SZ)   // 4096

// exp2-domain scale: 0.125 (1/sqrt(64)) * log2(e)
#define CF 0.180336880f
#define THRC 2.0f   // defer-max threshold in exp2 domain -> P bounded by 4

// ---------------------------------------------------------------------------
__device__ __forceinline__ void gload_lds16(const void* g, void* lds) {
    __builtin_amdgcn_global_load_lds(
        (const __attribute__((address_space(1))) void*)(uintptr_t)g,
        (__attribute__((address_space(3))) void*)(uint32_t)(uintptr_t)lds,
        16, 0, 0);
}

__device__ __forceinline__ f32x4 mfma16(bf16x8 a, bf16x8 b, f32x4 c) {
    return __builtin_amdgcn_mfma_f32_16x16x32_bf16(a, b, c, 0, 0, 0);
}
__device__ __forceinline__ f32x16 mfma32(bf16x8 a, bf16x8 b, f32x16 c) {
    return __builtin_amdgcn_mfma_f32_32x32x16_bf16(a, b, c, 0, 0, 0);
}
__device__ __forceinline__ int2v plswap(int a, int b) {
    return __builtin_amdgcn_permlane32_swap(a, b, false, false);
}
__device__ __forceinline__ int packbf(float a, float b) {
    bf16x2 t; t[0] = (bf16_t)a; t[1] = (bf16_t)b;
    return __builtin_bit_cast(int, t);
}

// ---------------------------------------------------------------------------
__global__ __launch_bounds__(256) void cast_f32_bf16(const float* __restrict__ in,
                                                     bf16_t* __restrict__ out) {
    size_t i = ((size_t)blockIdx.x * 256 + threadIdx.x) * 4;
    float4 v = *(const float4*)(in + i);
    bf16x4 o;
    o[0] = (bf16_t)v.x; o[1] = (bf16_t)v.y; o[2] = (bf16_t)v.z; o[3] = (bf16_t)v.w;
    *(bf16x4*)(out + i) = o;
}

// ---------------------------------------------------------------------------
__global__ __launch_bounds__(256) void transpose_cast_w(const float* __restrict__ W,
                                                        bf16_t* __restrict__ WT,
                                                        int K, int N) {
    __shared__ float t[32][33];
    int tid = threadIdx.x;
    int rr = tid >> 3, cc = (tid & 7) * 4;
    int k0 = blockIdx.x * 32, n0 = blockIdx.y * 32;
    float4 v = *(const float4*)(W + (size_t)(k0 + rr) * N + n0 + cc);
    t[rr][cc + 0] = v.x; t[rr][cc + 1] = v.y; t[rr][cc + 2] = v.z; t[rr][cc + 3] = v.w;
    __syncthreads();
    bf16x4 o;
    o[0] = (bf16_t)t[cc + 0][rr]; o[1] = (bf16_t)t[cc + 1][rr];
    o[2] = (bf16_t)t[cc + 2][rr]; o[3] = (bf16_t)t[cc + 3][rr];
    *(bf16x4*)(WT + (size_t)(n0 + rr) * K + k0 + cc) = o;
}

// ---------------------------------------------------------------------------
__global__ __launch_bounds__(256) void transpose_v(const bf16_t* __restrict__ Vp,
                                                   bf16_t* __restrict__ VT) {
    __shared__ bf16_t t[32][34];
    int tid = threadIdx.x;
    int rr = tid >> 3, cc = (tid & 7) * 4;
    int bh = blockIdx.z;
    int b = bh >> 4, h = bh & 15;
    int s0 = blockIdx.x * 32, d0 = blockIdx.y * 32;
    bf16x4 v = *(const bf16x4*)(Vp + ((size_t)(b * S_SZ + s0 + rr)) * D_MODEL + h * HEAD_DIM + d0 + cc);
    t[rr][cc + 0] = v[0]; t[rr][cc + 1] = v[1]; t[rr][cc + 2] = v[2]; t[rr][cc + 3] = v[3];
    __syncthreads();
    bf16x4 o;
    o[0] = t[cc + 0][rr]; o[1] = t[cc + 1][rr]; o[2] = t[cc + 2][rr]; o[3] = t[cc + 3][rr];
    *(bf16x4*)(VT + ((size_t)(bh * HEAD_DIM + d0 + rr)) * S_SZ + s0 + cc) = o;
}

// ---------------------------------------------------------------------------
// GEMM: C = A[:, koff:koff+Klen] @ Bt[:, koff:koff+Klen]^T (+bias on z==0)
// 128x128 tile, BK=32, 4 waves. Split-K via gridDim.z (partial f32 outputs).
// ---------------------------------------------------------------------------
template<bool RELU, bool OUT_BF16, bool OUT_F32>
__global__ __launch_bounds__(256) void gemm_bt(const bf16_t* __restrict__ A, int lda,
                                               const bf16_t* __restrict__ Bt, int ldb,
                                               const float* __restrict__ bias,
                                               float* __restrict__ Cf0,
                                               float* __restrict__ Cf1,
                                               bf16_t* __restrict__ Cb,
                                               int M, int N, int Klen) {
    __shared__ bf16_t sA[128 * 32];
    __shared__ bf16_t sB[128 * 32];
    const int tid = threadIdx.x;
    const int lane = tid & 63, wave = tid >> 6;
    const int g = lane >> 4, r = lane & 15;
    const int m0 = blockIdx.x * 128, n0 = blockIdx.y * 128;
    const int kz = blockIdx.z;
    const int koff = kz * Klen;
    const int wm = (wave >> 1) * 64, wn = (wave & 1) * 64;

    const bf16_t* Ablk = A + (size_t)m0 * lda + koff;
    const bf16_t* Bblk = Bt + (size_t)n0 * ldb + koff;
    const int c0 = wave * 64 + lane;
    const int c1 = c0 + 256;

    f32x4 acc[4][4];
#pragma unroll
    for (int i = 0; i < 4; i++)
#pragma unroll
        for (int j = 0; j < 4; j++)
#pragma unroll
            for (int e = 0; e < 4; e++) acc[i][j][e] = 0.f;

    for (int k0 = 0; k0 < Klen; k0 += 32) {
        gload_lds16(Ablk + (size_t)(c0 >> 2) * lda + k0 + (c0 & 3) * 8, sA + wave * 512);
        gload_lds16(Ablk + (size_t)(c1 >> 2) * lda + k0 + (c1 & 3) * 8, sA + 2048 + wave * 512);
        gload_lds16(Bblk + (size_t)(c0 >> 2) * ldb + k0 + (c0 & 3) * 8, sB + wave * 512);
        gload_lds16(Bblk + (size_t)(c1 >> 2) * ldb + k0 + (c1 & 3) * 8, sB + 2048 + wave * 512);
        __syncthreads();

        bf16x8 a[4], b[4];
#pragma unroll
        for (int i = 0; i < 4; i++)
            a[i] = *(const bf16x8*)(sA + (wm + i * 16 + r) * 32 + g * 8);
#pragma unroll
        for (int j = 0; j < 4; j++)
            b[j] = *(const bf16x8*)(sB + (wn + j * 16 + r) * 32 + g * 8);
#pragma unroll
        for (int i = 0; i < 4; i++)
#pragma unroll
            for (int j = 0; j < 4; j++)
                acc[i][j] = mfma16(a[i], b[j], acc[i][j]);
        __syncthreads();
    }

    float* Cf = kz ? Cf1 : Cf0;
#pragma unroll
    for (int j = 0; j < 4; j++) {
        int n = n0 + wn + j * 16 + r;
        float bv = (bias && kz == 0) ? bias[n] : 0.f;
#pragma unroll
        for (int i = 0; i < 4; i++) {
#pragma unroll
            for (int rr = 0; rr < 4; rr++) {
                int mrow = m0 + wm + i * 16 + g * 4 + rr;
                float val = acc[i][j][rr] + bv;
                if (RELU) val = fmaxf(val, 0.f);
                if (OUT_F32) Cf[(size_t)mrow * N + n] = val;
                if (OUT_BF16) Cb[(size_t)mrow * N + n] = (bf16_t)val;
            }
        }
    }
}

// ---------------------------------------------------------------------------
// Flash attention, 32x32 double-swapped, defer-max fast path.
// m tracked in exp2-domain (mC = m * 0.125 * log2e). l is an IN-LANE partial,
// cross-half-combined once at the end.
// ---------------------------------------------------------------------------
__device__ __forceinline__ void attn_tile32(
    const bf16_t* __restrict__ Kb, const bf16_t* __restrict__ Vb,
    int l31, int hi, int kvn,
    const bf16x8 (&bq)[4],
    bf16x8 (&ak)[4], bf16x8 (&av)[4],
    bf16x8 (&akn)[4], bf16x8 (&avn)[4],
    f32x16& o0, f32x16& o1, float& mC, float& l_run)
{
    // QK^T (swapped): s reg e -> E[kv = (e&3)+8*(e>>2)+4*hi][q = l31]
    f32x16 s;
#pragma unroll
    for (int e = 0; e < 16; e++) s[e] = 0.f;
    __builtin_amdgcn_s_setprio(1);
#pragma unroll
    for (int kb = 0; kb < 4; kb++) s = mfma32(ak[kb], bq[kb], s);
    __builtin_amdgcn_s_setprio(0);

    // prefetch next tile's K and V fragments
#pragma unroll
    for (int kb = 0; kb < 4; kb++)
        akn[kb] = *(const bf16x8*)(Kb + (size_t)(kvn + l31) * D_MODEL + kb * 16 + hi * 8);
#pragma unroll
    for (int db = 0; db < 2; db++)
#pragma unroll
        for (int kb = 0; kb < 2; kb++)
            avn[db * 2 + kb] = *(const bf16x8*)(Vb + (size_t)(db * 32 + l31) * S_SZ + kvn + kb * 16 + hi * 8);

    // in-lane max of 16
    float ma = fmaxf(fmaxf(s[0], s[1]), fmaxf(s[2], s[3]));
    float mb = fmaxf(fmaxf(s[4], s[5]), fmaxf(s[6], s[7]));
    float mc = fmaxf(fmaxf(s[8], s[9]), fmaxf(s[10], s[11]));
    float md = fmaxf(fmaxf(s[12], s[13]), fmaxf(s[14], s[15]));
    float pmaxC = fmaxf(fmaxf(ma, mb), fmaxf(mc, md)) * CF;

    // defer-max: __all spans all 64 lanes -> covers both kv halves
    if (!__all(pmaxC <= mC + THRC)) {
        // slow path: raise m to the cross-half row max
        int2v pr = plswap(__float_as_int(pmaxC), __float_as_int(pmaxC));
        float rowmaxC = fmaxf(__int_as_float(pr[0]), __int_as_float(pr[1]));
        float mnewC = fmaxf(mC, rowmaxC);
        float alpha = exp2f(mC - mnewC);
        mC = mnewC;
        l_run *= alpha;
#pragma unroll
        for (int e = 0; e < 16; e++) { o0[e] *= alpha; o1[e] *= alpha; }
    }

    // P = 2^(s*CF - mC); in-lane partial sum
#pragma unroll
    for (int e = 0; e < 16; e++) s[e] = exp2f(__builtin_fmaf(s[e], CF, -mC));
    float t0 = (s[0] + s[1]) + (s[2] + s[3]);
    float t1 = (s[4] + s[5]) + (s[6] + s[7]);
    float t2 = (s[8] + s[9]) + (s[10] + s[11]);
    float t3 = (s[12] + s[13]) + (s[14] + s[15]);
    l_run += (t0 + t1) + (t2 + t3);

    // pack P -> bf16 B-frags via permlane32_swap; PV
    __builtin_amdgcn_s_setprio(1);
#pragma unroll
    for (int kb2 = 0; kb2 < 2; kb2++) {
        const int bse = kb2 * 8;
        int W0 = packbf(s[bse + 0], s[bse + 1]);
        int W1 = packbf(s[bse + 2], s[bse + 3]);
        int W2 = packbf(s[bse + 4], s[bse + 5]);
        int W3 = packbf(s[bse + 6], s[bse + 7]);
        int2v r02 = plswap(W0, W2);
        int2v r13 = plswap(W1, W3);
        int4v fw; fw[0] = r02[0]; fw[1] = r13[0]; fw[2] = r02[1]; fw[3] = r13[1];
        bf16x8 pf = __builtin_bit_cast(bf16x8, fw);
        o0 = mfma32(av[kb2], pf, o0);
        o1 = mfma32(av[2 + kb2], pf, o1);
    }
    __builtin_amdgcn_s_setprio(0);
}

__global__ __launch_bounds__(256) void flash_attn(const bf16_t* __restrict__ Qp,
                                                  const bf16_t* __restrict__ Kp,
                                                  const bf16_t* __restrict__ VT,
                                                  bf16_t* __restrict__ Oa) {
    __shared__ float obuf[32][2][64];
    __shared__ float mrg[2][64][2];
    const int tid = threadIdx.x;
    const int lane = tid & 63;
    const int wave = tid >> 6;
    const int qt = wave >> 1, half = wave & 1;
    const int l31 = lane & 31, hi = lane >> 5;
    const int h = blockIdx.y, b = blockIdx.z;
    const int q0 = blockIdx.x * 64 + qt * 32;
    const int kvbase = half * (S_SZ / 2);

    const bf16_t* Qb = Qp + (size_t)b * S_SZ * D_MODEL + h * HEAD_DIM;
    const bf16_t* Kb = Kp + (size_t)b * S_SZ * D_MODEL + h * HEAD_DIM;
    const bf16_t* Vb = VT + ((size_t)(b * NUM_HEADS + h) * HEAD_DIM) * S_SZ;

    bf16x8 bq[4];
#pragma unroll
    for (int kb = 0; kb < 4; kb++)
        bq[kb] = *(const bf16x8*)(Qb + (size_t)(q0 + l31) * D_MODEL + kb * 16 + hi * 8);

    f32x16 o0, o1;
#pragma unroll
    for (int e = 0; e < 16; e++) { o0[e] = 0.f; o1[e] = 0.f; }
    float mC = -1e30f, l_run = 0.f;

    bf16x8 akA[4], akB[4], avA[4], avB[4];
#pragma unroll
    for (int kb = 0; kb < 4; kb++)
        akA[kb] = *(const bf16x8*)(Kb + (size_t)(kvbase + l31) * D_MODEL + kb * 16 + hi * 8);
#pragma unroll
    for (int db = 0; db < 2; db++)
#pragma unroll
        for (int kb = 0; kb < 2; kb++)
            avA[db * 2 + kb] = *(const bf16x8*)(Vb + (size_t)(db * 32 + l31) * S_SZ + kvbase + kb * 16 + hi * 8);

    for (int t = 0; t < 32; t += 2) {
        const int kv0 = kvbase + t * 32;
        attn_tile32(Kb, Vb, l31, hi, kv0 + 32, bq, akA, avA, akB, avB, o0, o1, mC, l_run);
        const int kvn2 = (t + 2 < 32) ? kv0 + 64 : kvbase;
        attn_tile32(Kb, Vb, l31, hi, kvn2, bq, akB, avB, akA, avA, o0, o1, mC, l_run);
    }

    // cross-half l combine (deferred from the main loop)
    int2v lp = plswap(__float_as_int(l_run), __float_as_int(l_run));
    l_run = __int_as_float(lp[0]) + __int_as_float(lp[1]);

    // split-KV merge
    if (half == 1) {
        mrg[qt][lane][0] = mC;
        mrg[qt][lane][1] = l_run;
#pragma unroll
        for (int e = 0; e < 16; e++) {
            obuf[e][qt][lane] = o0[e];
            obuf[16 + e][qt][lane] = o1[e];
        }
    }
    __syncthreads();
    if (half == 0) {
        const float m2C = mrg[qt][lane][0], l2 = mrg[qt][lane][1];
        const float mmC = fmaxf(mC, m2C);
        const float e1 = exp2f(mC - mmC);
        const float e2 = exp2f(m2C - mmC);
        const float linv = 1.f / (l_run * e1 + l2 * e2);
        bf16_t* Orow = Oa + ((size_t)b * S_SZ + q0 + l31) * D_MODEL + h * HEAD_DIM;
#pragma unroll
        for (int db = 0; db < 2; db++) {
#pragma unroll
            for (int rq = 0; rq < 4; rq++) {
                bf16x4 st;
#pragma unroll
                for (int i = 0; i < 4; i++) {
                    const int e = rq * 4 + i;
                    const float own = db ? o1[e] : o0[e];
                    const float oth = obuf[db * 16 + e][qt][lane];
                    st[i] = (bf16_t)((own * e1 + oth * e2) * linv);
                }
                *(bf16x4*)(Orow + db * 32 + rq * 8 + hi * 4) = st;
            }
        }
    }
}

// ---------------------------------------------------------------------------
// LayerNorm over 1024 with fused residual + optional second addend
// (split-K partial reduction folded in). 1 block = 1 row.
// ---------------------------------------------------------------------------
__global__ __launch_bounds__(256) void ln_fused(const float* __restrict__ A,
                                                const float* __restrict__ A2,
                                                const float* __restrict__ R,
                                                const float* __restrict__ gamma,
                                                const float* __restrict__ beta,
                                                float* __restrict__ Xf,
                                                bf16_t* __restrict__ Xb) {
    __shared__ float red[8];
    int row = blockIdx.x, tid = threadIdx.x;
    size_t base = (size_t)row * D_MODEL + tid * 4;
    float4 a = *(const float4*)(A + base);
    float4 rv = *(const float4*)(R + base);
    float v0 = a.x + rv.x, v1 = a.y + rv.y, v2 = a.z + rv.z, v3 = a.w + rv.w;
    if (A2) {
        float4 a2 = *(const float4*)(A2 + base);
        v0 += a2.x; v1 += a2.y; v2 += a2.z; v3 += a2.w;
    }
    float s = v0 + v1 + v2 + v3;
    float q = v0 * v0 + v1 * v1 + v2 * v2 + v3 * v3;
#pragma unroll
    for (int off = 32; off; off >>= 1) { s += __shfl_down(s, off); q += __shfl_down(q, off); }
    if ((tid & 63) == 0) { red[tid >> 6] = s; red[4 + (tid >> 6)] = q; }
    __syncthreads();
    s = red[0] + red[1] + red[2] + red[3];
    q = red[4] + red[5] + red[6] + red[7];
    float mean = s * (1.f / D_MODEL);
    float var = q * (1.f / D_MODEL) - mean * mean;
    float rstd = rsqrtf(var + 1e-5f);
    float4 gm = *(const float4*)(gamma + tid * 4);
    float4 bt = *(const float4*)(beta + tid * 4);
    float y0 = (v0 - mean) * rstd * gm.x + bt.x;
    float y1 = (v1 - mean) * rstd * gm.y + bt.y;
    float y2 = (v2 - mean) * rstd * gm.z + bt.z;
    float y3 = (v3 - mean) * rstd * gm.w + bt.w;
    float4 yo; yo.x = y0; yo.y = y1; yo.z = y2; yo.w = y3;
    *(float4*)(Xf + base) = yo;
    if (Xb) {
        bf16x4 ob; ob[0] = (bf16_t)y0; ob[1] = (bf16_t)y1; ob[2] = (bf16_t)y2; ob[3] = (bf16_t)y3;
        *(bf16x4*)(Xb + base) = ob;
    }
}

// ---------------------------------------------------------------------------
extern "C" void kernel_launch(void* const* d_in, const int* in_sizes, int n_in,
                              void* d_out, int out_size, void* d_ws, size_t ws_size,
                              hipStream_t stream) {
    const float* value = (const float*)d_in[0];
    const float* key   = (const float*)d_in[1];
    const float* query = (const float*)d_in[2];
    const float* wq = (const float*)d_in[3];
    const float* bq = (const float*)d_in[4];
    const float* wk = (const float*)d_in[5];
    const float* bk = (const float*)d_in[6];
    const float* wv = (const float*)d_in[7];
    const float* bv = (const float*)d_in[8];
    const float* wo = (const float*)d_in[9];
    const float* bo = (const float*)d_in[10];
    const float* g1 = (const float*)d_in[11];
    const float* beta1 = (const float*)d_in[12];
    const float* w1 = (const float*)d_in[13];
    const float* b1 = (const float*)d_in[14];
    const float* w2 = (const float*)d_in[15];
    const float* b2 = (const float*)d_in[16];
    const float* g2 = (const float*)d_in[17];
    const float* beta2 = (const float*)d_in[18];
    (void)in_sizes; (void)n_in; (void)out_size; (void)ws_size;

    const size_t MB = 1ull << 20;
    char* ws = (char*)d_ws;
    // lifetime-packed layout (max 112 MB)
    bf16_t* wqT = (bf16_t*)(ws + 0 * MB);
    bf16_t* wkT = (bf16_t*)(ws + 2 * MB);
    bf16_t* wvT = (bf16_t*)(ws + 4 * MB);
    bf16_t* woT = (bf16_t*)(ws + 6 * MB);
    bf16_t* w1T = (bf16_t*)(ws + 8 * MB);
    bf16_t* w2T = (bf16_t*)(ws + 16 * MB);
    bf16_t* q_bf = (bf16_t*)(ws + 24 * MB);
    bf16_t* k_bf = (bf16_t*)(ws + 32 * MB);
    bf16_t* v_bf = (bf16_t*)(ws + 40 * MB);
    bf16_t* Qp  = (bf16_t*)(ws + 48 * MB);
    bf16_t* Kp  = (bf16_t*)(ws + 56 * MB);
    bf16_t* Vp  = (bf16_t*)(ws + 64 * MB);
    bf16_t* VT  = (bf16_t*)(ws + 72 * MB);
    bf16_t* attn = (bf16_t*)(ws + 24 * MB);   // reuse q_bf (dead after QKV gemm)
    float*  woP0 = (float*)(ws + 32 * MB);    // reuse k_bf..Qp (dead after flash)
    float*  woP1 = (float*)(ws + 48 * MB);
    float*  x_f = (float*)(ws + 64 * MB);     // reuse Vp/VT (dead after flash)
    bf16_t* x_b = (bf16_t*)(ws + 24 * MB);    // reuse attn (dead after WO gemm)
    bf16_t* h_b = (bf16_t*)(ws + 32 * MB);    // reuse woP (dead after LN1), 32MB
    float*  ffP0 = (float*)(ws + 80 * MB);
    float*  ffP1 = (float*)(ws + 96 * MB);

    dim3 blk(256);

    // 1) casts + weight transposes
    cast_f32_bf16<<<4096, blk, 0, stream>>>(query, q_bf);
    cast_f32_bf16<<<4096, blk, 0, stream>>>(key, k_bf);
    cast_f32_bf16<<<4096, blk, 0, stream>>>(value, v_bf);
    transpose_cast_w<<<dim3(32, 32), blk, 0, stream>>>(wq, wqT, 1024, 1024);
    transpose_cast_w<<<dim3(32, 32), blk, 0, stream>>>(wk, wkT, 1024, 1024);
    transpose_cast_w<<<dim3(32, 32), blk, 0, stream>>>(wv, wvT, 1024, 1024);
    transpose_cast_w<<<dim3(32, 32), blk, 0, stream>>>(wo, woT, 1024, 1024);
    transpose_cast_w<<<dim3(32, 128), blk, 0, stream>>>(w1, w1T, 1024, 4096);
    transpose_cast_w<<<dim3(128, 32), blk, 0, stream>>>(w2, w2T, 4096, 1024);

    // 2) QKV projections (bf16 out)
    gemm_bt<false, true, false><<<dim3(32, 8, 1), blk, 0, stream>>>(q_bf, 1024, wqT, 1024, bq, nullptr, nullptr, Qp, M_ROWS, D_MODEL, 1024);
    gemm_bt<false, true, false><<<dim3(32, 8, 1), blk, 0, stream>>>(k_bf, 1024, wkT, 1024, bk, nullptr, nullptr, Kp, M_ROWS, D_MODEL, 1024);
    gemm_bt<false, true, false><<<dim3(32, 8, 1), blk, 0, stream>>>(v_bf, 1024, wvT, 1024, bv, nullptr, nullptr, Vp, M_ROWS, D_MODEL, 1024);

    // 3) V transpose for PV A-operand
    transpose_v<<<dim3(64, 2, 32), blk, 0, stream>>>(Vp, VT);

    // 4) flash attention
    flash_attn<<<dim3(32, 16, 2), blk, 0, stream>>>(Qp, Kp, VT, attn);

    // 5) WO projection, split-K=2 (f32 partials)
    gemm_bt<false, false, true><<<dim3(32, 8, 2), blk, 0, stream>>>(attn, 1024, woT, 1024, bo, woP0, woP1, nullptr, M_ROWS, D_MODEL, 512);

    // 6) LN1: x = LN(woP0 + woP1 + query)
    ln_fused<<<4096, blk, 0, stream>>>(woP0, woP1, query, g1, beta1, x_f, x_b);

    // 7) FF1 + ReLU (bf16 out)
    gemm_bt<true, true, false><<<dim3(32, 32, 1), blk, 0, stream>>>(x_b, 1024, w1T, 1024, b1, nullptr, nullptr, h_b, M_ROWS, FF_DIM, 1024);

    // 8) FF2, split-K=2 (f32 partials)
    gemm_bt<false, false, true><<<dim3(32, 8, 2), blk, 0, stream>>>(h_b, 4096, w2T, 4096, b2, ffP0, ffP1, nullptr, M_ROWS, D_MODEL, 2048);

    // 9) LN2 -> d_out
    ln_fused<<<4096, blk, 0, stream>>>(ffP0, ffP1, x_f, g2, beta2, (float*)d_out, nullptr);
}